// Round 2
// baseline (608.897 us; speedup 1.0000x reference)
//
#include <hip/hip_runtime.h>
#include <math.h>

#define NN 25000
#define NE 400000

#define C_S 0.3826834323650898f
#define C_X 0.9238795325112867f
#define INV_SQRT3 0.5773502691896258f
#define INV_M 0.125f
#define INV_2M 0.08838834764831845f
#define INV_NB 0.25f
#define INV_SQRT_NB 0.3535533905932738f

// ---------------- Kernel A: s = x@W_sc, h = x@W_lin1 (per node) ----------------
// 8 waves/block cooperate on one node. wave0: s0, wave1: h0, waves2-4: s1 c,
// waves5-7: h1 c. Weight column in 64 VGPRs/lane. hbuf row = [u][4] =
// {h0, h1c0, h1c1, h1c2} so the edge kernel gathers one float4/lane.
__global__ __launch_bounds__(512) void node_linear1(
    const float* __restrict__ node_input, const float* __restrict__ node_attr,
    const float* __restrict__ W_sc0, const float* __restrict__ W_sc1,
    const float* __restrict__ W_l10, const float* __restrict__ W_l11,
    float* __restrict__ out, float* __restrict__ hbuf)
{
    __shared__ float xrow[64];
    __shared__ float xT[192];   // xT[c*64+u] = x1[u][c]
    __shared__ float orow[256];
    __shared__ float hrow[256];
    const int tid = threadIdx.x;
    const int wave = tid >> 6;
    const int lane = tid & 63;
    const float* Wm;
    int chan = 0;
    if (wave == 0)      Wm = W_sc0;
    else if (wave == 1) Wm = W_l10;
    else if (wave <= 4) { Wm = W_sc1; chan = wave - 2; }
    else                { Wm = W_l11; chan = wave - 5; }
    float wcol[64];
#pragma unroll
    for (int u = 0; u < 64; ++u) wcol[u] = Wm[u * 64 + lane];

    for (int n = blockIdx.x; n < NN; n += gridDim.x) {
        if (tid < 64) xrow[tid] = node_input[n * 256 + tid];
        else if (tid < 256) {
            float v = node_input[n * 256 + tid];
            int j = tid - 64;              // j = u*3 + c
            xT[(j % 3) * 64 + (j / 3)] = v;
        }
        __syncthreads();
        float z = node_attr[n];
        const float* xv = (wave < 2) ? xrow : (xT + chan * 64);
        float acc = 0.f;
#pragma unroll
        for (int u = 0; u < 64; u += 4) {
            float4 x4 = *reinterpret_cast<const float4*>(xv + u);
            acc = fmaf(x4.x, wcol[u + 0], acc);
            acc = fmaf(x4.y, wcol[u + 1], acc);
            acc = fmaf(x4.z, wcol[u + 2], acc);
            acc = fmaf(x4.w, wcol[u + 3], acc);
        }
        acc *= INV_M * z;
        if (wave == 0)      orow[lane] = C_S * acc;
        else if (wave == 1) hrow[lane * 4 + 0] = acc;
        else if (wave <= 4) orow[64 + lane * 3 + chan] = C_S * acc;
        else                hrow[lane * 4 + 1 + chan] = acc;
        __syncthreads();
        if (tid < 256) out[n * 256 + tid] = orow[tid];
        else           hbuf[n * 256 + (tid - 256)] = hrow[tid - 256];
        __syncthreads();
    }
}

// ---------------- CSR build ----------------
__global__ void zero_counts(int* counts) {
    int i = blockIdx.x * blockDim.x + threadIdx.x;
    if (i < NN) counts[i] = 0;
}
__global__ void hist_kernel(const int* __restrict__ edge_dst, int* __restrict__ counts) {
    for (int i = blockIdx.x * blockDim.x + threadIdx.x; i < NE; i += gridDim.x * blockDim.x)
        atomicAdd(&counts[edge_dst[i]], 1);
}
__global__ __launch_bounds__(1024) void scan_kernel(const int* __restrict__ counts,
                                                    int* __restrict__ row_start,
                                                    int* __restrict__ cursor)
{
    __shared__ int partial[1024];
    const int tid = threadIdx.x;
    const int CH = 25;                     // 1024*25 >= 25000
    int begin = tid * CH;
    int end = begin + CH; if (end > NN) end = NN;
    if (begin > NN) begin = NN;
    int s = 0;
    for (int i = begin; i < end; ++i) s += counts[i];
    partial[tid] = s;
    __syncthreads();
    for (int off = 1; off < 1024; off <<= 1) {
        int v = partial[tid];
        int a = (tid >= off) ? partial[tid - off] : 0;
        __syncthreads();
        partial[tid] = v + a;
        __syncthreads();
    }
    int run = (tid > 0) ? partial[tid - 1] : 0;
    for (int i = begin; i < end; ++i) {
        row_start[i] = run;
        cursor[i] = run;
        run += counts[i];
    }
    if (tid == 1023) row_start[NN] = partial[1023];
}
__global__ void scatter_kernel(const int* __restrict__ edge_dst, int* __restrict__ cursor,
                               int* __restrict__ csr) {
    for (int i = blockIdx.x * blockDim.x + threadIdx.x; i < NE; i += gridDim.x * blockDim.x) {
        int p = atomicAdd(&cursor[edge_dst[i]], 1);
        csr[p] = i;
    }
}

// ---------------- Kernel E: per-dst-node edge MLP + gather + reduce ----------------
// One wave per node; lane u = output mul channel. fc_w1 packed in LDS as
// [v][u][ABCD] -> one ds_read_b128/lane/v, amortized over EIGHT edges
// (64 KB LDS weight reads per 8 edges -> 3.2 GB total, under the VALU floor).
// Gathers for edges 4-7 issued after the w-loop, consumed after epilogue 0-3,
// so HBM/L3 latency hides under live FMAs. No atomics anywhere.
__global__ __launch_bounds__(512) void edge_reduce(
    const float* __restrict__ elemb, const float* __restrict__ edge_attr,
    const float* __restrict__ fc_w0, const float* __restrict__ fc_w1,
    const int* __restrict__ edge_src,
    const int* __restrict__ csr, const int* __restrict__ row_start,
    const float* __restrict__ hbuf, float* __restrict__ ybuf)
{
    __shared__ float fcw1p[16384];   // [v][u][k], pre-scaled by 1/sqrt(RN)=0.125
    __shared__ float hidb[8][512];   // per-wave: [v*8+ee]
    const int tid = threadIdx.x, wave = tid >> 6, lane = tid & 63;
    for (int i = tid; i < 16384; i += 512) {
        int v = i >> 8, j = i & 255, k = j >> 6, u = j & 63;
        fcw1p[v * 256 + u * 4 + k] = fc_w1[i] * 0.125f;
    }
    float fw0[8];
#pragma unroll
    for (int b = 0; b < 8; ++b) fw0[b] = fc_w0[b * 64 + lane];
    __syncthreads();

    for (int n = blockIdx.x * 8 + wave; n < NN; n += gridDim.x * 8) {
        int row = __builtin_amdgcn_readfirstlane(row_start[n]);
        int cnt = __builtin_amdgcn_readfirstlane(row_start[n + 1]) - row;
        float accA = 0.f, accD = 0.f;
        float accB0 = 0.f, accB1 = 0.f, accB2 = 0.f;
        float accC0 = 0.f, accC1 = 0.f, accC2 = 0.f;
        for (int base = 0; base < cnt; base += 8) {
            int e[8];
            float hid[8];
#pragma unroll
            for (int ee = 0; ee < 8; ++ee) {
                if (base + ee < cnt) {           // wave-uniform condition
                    int ev = __builtin_amdgcn_readfirstlane(csr[row + base + ee]);
                    e[ee] = ev;
                    float4 b0 = *reinterpret_cast<const float4*>(elemb + (long)ev * 8);
                    float4 b1 = *reinterpret_cast<const float4*>(elemb + (long)ev * 8 + 4);
                    float d = b0.x * fw0[0] + b0.y * fw0[1] + b0.z * fw0[2] + b0.w * fw0[3]
                            + b1.x * fw0[4] + b1.y * fw0[5] + b1.z * fw0[6] + b1.w * fw0[7];
                    d *= INV_SQRT_NB;
                    hid[ee] = d / (1.f + __expf(-d));
                } else {
                    e[ee] = 0;                   // safe addr; hid=0 -> w=0 -> no contribution
                    hid[ee] = 0.f;
                }
            }
            // lane = hidden unit v; two b128 writes, uniform 8 dwords/bank
            *reinterpret_cast<float4*>(&hidb[wave][lane * 8]) =
                make_float4(hid[0], hid[1], hid[2], hid[3]);
            *reinterpret_cast<float4*>(&hidb[wave][lane * 8 + 4]) =
                make_float4(hid[4], hid[5], hid[6], hid[7]);
            // gathers for edges 0-3 (latency hidden under the w-loop)
            float4 xs[4], sh[4];
#pragma unroll
            for (int ee = 0; ee < 4; ++ee) {
                int src = __builtin_amdgcn_readfirstlane(edge_src[e[ee]]);
                xs[ee] = *reinterpret_cast<const float4*>(hbuf + (long)src * 256 + lane * 4);
                sh[ee] = *reinterpret_cast<const float4*>(edge_attr + (long)e[ee] * 4);
            }
            float wAc[8] = {0,0,0,0,0,0,0,0}, wBc[8] = {0,0,0,0,0,0,0,0};
            float wCc[8] = {0,0,0,0,0,0,0,0}, wDc[8] = {0,0,0,0,0,0,0,0};
#pragma unroll 8
            for (int v = 0; v < 64; ++v) {
                float4 wv = *reinterpret_cast<const float4*>(&fcw1p[v * 256 + lane * 4]); // contiguous
                float4 h0 = *reinterpret_cast<const float4*>(&hidb[wave][v * 8]);         // broadcast
                float4 h1 = *reinterpret_cast<const float4*>(&hidb[wave][v * 8 + 4]);     // broadcast
                float ha[8] = {h0.x, h0.y, h0.z, h0.w, h1.x, h1.y, h1.z, h1.w};
#pragma unroll
                for (int ee = 0; ee < 8; ++ee) {
                    wAc[ee] = fmaf(wv.x, ha[ee], wAc[ee]);
                    wBc[ee] = fmaf(wv.y, ha[ee], wBc[ee]);
                    wCc[ee] = fmaf(wv.z, ha[ee], wCc[ee]);
                    wDc[ee] = fmaf(wv.w, ha[ee], wDc[ee]);
                }
            }
            // gathers for edges 4-7; consumed after epilogue 0-3
            float4 xs2[4], sh2[4];
#pragma unroll
            for (int ee = 0; ee < 4; ++ee) {
                int src = __builtin_amdgcn_readfirstlane(edge_src[e[ee + 4]]);
                xs2[ee] = *reinterpret_cast<const float4*>(hbuf + (long)src * 256 + lane * 4);
                sh2[ee] = *reinterpret_cast<const float4*>(edge_attr + (long)e[ee + 4] * 4);
            }
#pragma unroll
            for (int ee = 0; ee < 4; ++ee) {
                float x0 = xs[ee].x, x1a = xs[ee].y, x1b = xs[ee].z, x1c = xs[ee].w;
                float s0 = sh[ee].x, s1x = sh[ee].y, s1y = sh[ee].z, s1z = sh[ee].w;
                accA = fmaf(wAc[ee] * x0, s0, accA);
                float dot3 = x1a * s1x + x1b * s1y + x1c * s1z;
                accD = fmaf(wDc[ee], dot3, accD);
                float wbx = wBc[ee] * x0;
                accB0 = fmaf(wbx, s1x, accB0);
                accB1 = fmaf(wbx, s1y, accB1);
                accB2 = fmaf(wbx, s1z, accB2);
                float wcs = wCc[ee] * s0;
                accC0 = fmaf(wcs, x1a, accC0);
                accC1 = fmaf(wcs, x1b, accC1);
                accC2 = fmaf(wcs, x1c, accC2);
            }
#pragma unroll
            for (int ee = 0; ee < 4; ++ee) {
                float x0 = xs2[ee].x, x1a = xs2[ee].y, x1b = xs2[ee].z, x1c = xs2[ee].w;
                float s0 = sh2[ee].x, s1x = sh2[ee].y, s1y = sh2[ee].z, s1z = sh2[ee].w;
                accA = fmaf(wAc[ee + 4] * x0, s0, accA);
                float dot3 = x1a * s1x + x1b * s1y + x1c * s1z;
                accD = fmaf(wDc[ee + 4], dot3, accD);
                float wbx = wBc[ee + 4] * x0;
                accB0 = fmaf(wbx, s1x, accB0);
                accB1 = fmaf(wbx, s1y, accB1);
                accB2 = fmaf(wbx, s1z, accB2);
                float wcs = wCc[ee + 4] * s0;
                accC0 = fmaf(wcs, x1a, accC0);
                accC1 = fmaf(wcs, x1b, accC1);
                accC2 = fmaf(wcs, x1c, accC2);
            }
        }
        // y row layout: [A(64) | D(64) | c0:{B,C} | c1:{B,C} | c2:{B,C}] = 512 floats
        float* yr = ybuf + (long)n * 512;
        yr[lane]       = accA * INV_NB;
        yr[64 + lane]  = accD * (INV_NB * INV_SQRT3);
        yr[128 + lane] = accB0 * INV_NB;
        yr[192 + lane] = accC0 * INV_NB;
        yr[256 + lane] = accB1 * INV_NB;
        yr[320 + lane] = accC1 * INV_NB;
        yr[384 + lane] = accB2 * INV_NB;
        yr[448 + lane] = accC2 * INV_NB;
    }
}

// ---------------- Kernel F: o = y @ W_lin2, out += c_x * o ----------------
__global__ __launch_bounds__(256) void node_linear2(
    const float* __restrict__ ybuf, const float* __restrict__ node_attr,
    const float* __restrict__ W20, const float* __restrict__ W21,
    float* __restrict__ out)
{
    __shared__ float yrow[512];
    const int tid = threadIdx.x, wave = tid >> 6, lane = tid & 63;
    const float* Wm = (wave == 0) ? W20 : W21;
    float wc[128];
#pragma unroll
    for (int j = 0; j < 128; ++j) wc[j] = Wm[j * 64 + lane];
    for (int n = blockIdx.x; n < NN; n += gridDim.x) {
        yrow[tid]       = ybuf[(long)n * 512 + tid];
        yrow[256 + tid] = ybuf[(long)n * 512 + 256 + tid];
        __syncthreads();
        float z = node_attr[n];
        const float* yv = (wave == 0) ? yrow : (yrow + 128 + (wave - 1) * 128);
        float acc = 0.f;
#pragma unroll
        for (int j = 0; j < 128; j += 4) {
            float4 y4 = *reinterpret_cast<const float4*>(yv + j);
            acc = fmaf(y4.x, wc[j + 0], acc);
            acc = fmaf(y4.y, wc[j + 1], acc);
            acc = fmaf(y4.z, wc[j + 2], acc);
            acc = fmaf(y4.w, wc[j + 3], acc);
        }
        acc *= C_X * INV_2M * z;
        int oidx = (wave == 0) ? (n * 256 + lane) : (n * 256 + 64 + lane * 3 + (wave - 1));
        out[oidx] += acc;     // out already holds c_s * s from kernel A
        __syncthreads();
    }
}

extern "C" void kernel_launch(void* const* d_in, const int* in_sizes, int n_in,
                              void* d_out, int out_size, void* d_ws, size_t ws_size,
                              hipStream_t stream)
{
    (void)in_sizes; (void)n_in; (void)out_size; (void)ws_size;
    const float* node_input = (const float*)d_in[0];
    const float* node_attr  = (const float*)d_in[1];
    const int*   edge_src   = (const int*)d_in[2];
    const int*   edge_dst   = (const int*)d_in[3];
    const float* edge_attr  = (const float*)d_in[4];
    const float* elemb      = (const float*)d_in[5];
    const float* W_sc0      = (const float*)d_in[6];
    const float* W_sc1      = (const float*)d_in[7];
    const float* W_l10      = (const float*)d_in[8];
    const float* W_l11      = (const float*)d_in[9];
    const float* fc_w0      = (const float*)d_in[10];
    const float* fc_w1      = (const float*)d_in[11];
    const float* W20        = (const float*)d_in[12];
    const float* W21        = (const float*)d_in[13];
    float* out = (float*)d_out;

    // workspace: hbuf 25.6MB | ybuf 51.2MB | counts | row_start | cursor | csr  (~79MB)
    float* hbuf = (float*)d_ws;
    float* ybuf = hbuf + (size_t)NN * 256;
    int* counts    = (int*)(ybuf + (size_t)NN * 512);
    int* row_start = counts + NN;
    int* cursor    = row_start + NN + 8;
    int* csr       = cursor + NN;

    node_linear1<<<1024, 512, 0, stream>>>(node_input, node_attr, W_sc0, W_sc1,
                                           W_l10, W_l11, out, hbuf);
    zero_counts<<<(NN + 255) / 256, 256, 0, stream>>>(counts);
    hist_kernel<<<1024, 256, 0, stream>>>(edge_dst, counts);
    scan_kernel<<<1, 1024, 0, stream>>>(counts, row_start, cursor);
    scatter_kernel<<<1024, 256, 0, stream>>>(edge_dst, cursor, csr);
    edge_reduce<<<512, 512, 0, stream>>>(elemb, edge_attr, fc_w0, fc_w1, edge_src,
                                         csr, row_start, hbuf, ybuf);
    node_linear2<<<1024, 256, 0, stream>>>(ybuf, node_attr, W20, W21, out);
}